// Round 1
// baseline (870.843 us; speedup 1.0000x reference)
//
#include <hip/hip_runtime.h>
#include <math.h>

#define NNODES 100000
#define NEDGES 3200000
#define ETOT   (NEDGES + NNODES)
#define IN_DIM 128
#define NH1    8
#define NC1    8
#define HC     64
#define OUTC   2
#define NEGSL  0.2f

// ---------------- CSR build ----------------

__global__ void zero_ints(int* p, int n) {
    int i = blockIdx.x * blockDim.x + threadIdx.x;
    if (i < n) p[i] = 0;
}

__global__ void hist_kernel(const int* ei, int* cnt) {
    int i = blockIdx.x * blockDim.x + threadIdx.x;
    if (i < NEDGES) atomicAdd(&cnt[ei[NEDGES + i]], 1);
}

// exclusive scan of (cnt[i] + 1) -> rowoff (block-local), block totals -> bsums
__global__ __launch_bounds__(256) void scan1(const int* cnt, int* rowoff, int* bsums) {
    int gid = blockIdx.x * 256 + threadIdx.x;
    int v = (gid < NNODES) ? (cnt[gid] + 1) : 0;   // +1 self-loop per node
    int lane = threadIdx.x & 63, w = threadIdx.x >> 6;
    int x = v;
    for (int off = 1; off < 64; off <<= 1) {
        int y = __shfl_up(x, off, 64);
        if (lane >= off) x += y;
    }
    __shared__ int wtot[4];
    if (lane == 63) wtot[w] = x;
    __syncthreads();
    int add = 0;
    for (int i = 0; i < w; i++) add += wtot[i];
    int incl = x + add;
    if (gid < NNODES) rowoff[gid] = incl - v;      // exclusive within block
    if (threadIdx.x == 255) bsums[blockIdx.x] = incl;
}

__global__ __launch_bounds__(512) void scan2(int* bsums, int nb) {
    int tid = threadIdx.x;
    int v = (tid < nb) ? bsums[tid] : 0;
    int lane = tid & 63, w = tid >> 6;
    int x = v;
    for (int off = 1; off < 64; off <<= 1) {
        int y = __shfl_up(x, off, 64);
        if (lane >= off) x += y;
    }
    __shared__ int wt[8];
    if (lane == 63) wt[w] = x;
    __syncthreads();
    int add = 0;
    for (int i = 0; i < w; i++) add += wt[i];
    if (tid < nb) bsums[tid] = x + add - v;        // exclusive
}

__global__ void scan3(int* rowoff, const int* bsums, int* cursor) {
    int gid = blockIdx.x * blockDim.x + threadIdx.x;
    if (gid < NNODES) {
        int r = rowoff[gid] + bsums[gid >> 8];
        rowoff[gid] = r;
        cursor[gid] = r;
    }
    if (gid == 0) rowoff[NNODES] = ETOT;
}

__global__ void scatter_kernel(const int* ei, int* cursor, int* srcs) {
    int i = blockIdx.x * blockDim.x + threadIdx.x;
    if (i >= ETOT) return;
    int s, d;
    if (i < NEDGES) { s = ei[i]; d = ei[NEDGES + i]; }
    else            { s = d = i - NEDGES; }
    int pos = atomicAdd(&cursor[d], 1);
    srcs[pos] = s;
}

// ---------------- layer 1 linear + attention logits ----------------
// h1[n][hc] = sum_k x[n][k] * W1[k][hc];  al1s/al1d[n][h] = sum_c h*a

__global__ __launch_bounds__(256) void gemm1(const float* __restrict__ x,
                                             const float* __restrict__ W1,
                                             const float* __restrict__ a1s,
                                             const float* __restrict__ a1d,
                                             float* __restrict__ h1,
                                             float* __restrict__ al1s,
                                             float* __restrict__ al1d) {
    __shared__ float sW[IN_DIM * HC];   // 32 KB
    __shared__ float sx[4][IN_DIM];     // 2 KB
    int tid = threadIdx.x;
    for (int i = tid; i < IN_DIM * HC; i += 256) sW[i] = W1[i];
    int node0 = blockIdx.x * 4;
    for (int i = tid; i < 4 * IN_DIM; i += 256) {
        int nn = node0 + (i >> 7);
        sx[i >> 7][i & 127] = (nn < NNODES) ? x[(size_t)nn * IN_DIM + (i & 127)] : 0.f;
    }
    __syncthreads();
    int w = tid >> 6, lane = tid & 63;
    int node = node0 + w;
    float acc = 0.f;
#pragma unroll 8
    for (int k = 0; k < IN_DIM; k++) acc += sx[w][k] * sW[k * HC + lane];
    if (node < NNODES) {
        h1[(size_t)node * HC + lane] = acc;
        int head = lane >> 3, c = lane & 7;
        float ps = acc * a1s[head * NC1 + c];
        float pd = acc * a1d[head * NC1 + c];
        for (int off = 1; off < 8; off <<= 1) {
            ps += __shfl_xor(ps, off, 64);
            pd += __shfl_xor(pd, off, 64);
        }
        if (c == 0) {
            al1s[node * NH1 + head] = ps;
            al1d[node * NH1 + head] = pd;
        }
    }
}

// ---------------- layer 1 aggregation (wave per node, online softmax)
//                  + fused finalize + layer-2 linear/logits ----------------

__global__ __launch_bounds__(256) void agg1(const float* __restrict__ h1,
                                            const float* __restrict__ al1s,
                                            const float* __restrict__ al1d,
                                            const float* __restrict__ b1,
                                            const float* __restrict__ W2,
                                            const float* __restrict__ a2s,
                                            const float* __restrict__ a2d,
                                            const int* __restrict__ rowoff,
                                            const int* __restrict__ srcs,
                                            float* __restrict__ h2,
                                            float* __restrict__ al2s,
                                            float* __restrict__ al2d) {
    int w = threadIdx.x >> 6, lane = threadIdx.x & 63;
    int node = blockIdx.x * 4 + w;
    if (node >= NNODES) return;
    int head = lane >> 3;
    float ald = al1d[node * NH1 + head];
    int beg = rowoff[node], end = rowoff[node + 1];
    float m = -1e30f, den = 0.f, acc = 0.f;
    for (int i = beg; i < end; i++) {
        int s = srcs[i];
        float als = al1s[s * NH1 + head];
        float hv = h1[(size_t)s * HC + lane];
        float e = als + ald;
        e = (e > 0.f) ? e : NEGSL * e;
        float mn = fmaxf(m, e);
        float sc = __expf(m - mn);
        float p  = __expf(e - mn);
        den = den * sc + p;
        acc = acc * sc + p * hv;
        m = mn;
    }
    float o = acc / den + b1[lane];
    o = (o > 0.f) ? o : expm1f(o);          // ELU
    // layer-2 linear: h2[node][oc] = sum_lane o * W2[lane][oc]
    float p0 = o * W2[lane * OUTC + 0];
    float p1 = o * W2[lane * OUTC + 1];
    for (int off = 1; off < 64; off <<= 1) {
        p0 += __shfl_xor(p0, off, 64);
        p1 += __shfl_xor(p1, off, 64);
    }
    if (lane == 0) {
        h2[node * 2 + 0] = p0;
        h2[node * 2 + 1] = p1;
        al2s[node] = p0 * a2s[0] + p1 * a2s[1];
        al2d[node] = p0 * a2d[0] + p1 * a2d[1];
    }
}

// ---------------- layer 2 aggregation (thread per node) ----------------

__global__ void agg2(const float* __restrict__ h2,
                     const float* __restrict__ al2s,
                     const float* __restrict__ al2d,
                     const float* __restrict__ b2,
                     const int* __restrict__ rowoff,
                     const int* __restrict__ srcs,
                     float* __restrict__ out) {
    int n = blockIdx.x * blockDim.x + threadIdx.x;
    if (n >= NNODES) return;
    float ald = al2d[n];
    int beg = rowoff[n], end = rowoff[n + 1];
    float m = -1e30f, den = 0.f, a0 = 0.f, a1 = 0.f;
    for (int i = beg; i < end; i++) {
        int s = srcs[i];
        float e = al2s[s] + ald;
        e = (e > 0.f) ? e : NEGSL * e;
        float mn = fmaxf(m, e);
        float sc = __expf(m - mn);
        float p  = __expf(e - mn);
        den = den * sc + p;
        a0 = a0 * sc + p * h2[s * 2 + 0];
        a1 = a1 * sc + p * h2[s * 2 + 1];
        m = mn;
    }
    out[n * 2 + 0] = a0 / den + b2[0];
    out[n * 2 + 1] = a1 / den + b2[1];
}

// ---------------- launch ----------------

extern "C" void kernel_launch(void* const* d_in, const int* in_sizes, int n_in,
                              void* d_out, int out_size, void* d_ws, size_t ws_size,
                              hipStream_t stream) {
    const float* x   = (const float*)d_in[0];
    const int*   ei  = (const int*)  d_in[1];
    // d_in[2] = edge_attr (unused by reference)
    const float* W1  = (const float*)d_in[3];
    const float* a1s = (const float*)d_in[4];
    const float* a1d = (const float*)d_in[5];
    const float* b1  = (const float*)d_in[6];
    const float* W2  = (const float*)d_in[7];
    const float* a2s = (const float*)d_in[8];
    const float* a2d = (const float*)d_in[9];
    const float* b2  = (const float*)d_in[10];
    float* out = (float*)d_out;

    // workspace layout
    float* fws   = (float*)d_ws;
    float* h1    = fws;                                 // N*64
    float* al1s_ = h1 + (size_t)NNODES * HC;            // N*8
    float* al1d_ = al1s_ + (size_t)NNODES * NH1;        // N*8
    float* h2    = al1d_ + (size_t)NNODES * NH1;        // N*2
    float* al2s_ = h2 + (size_t)NNODES * 2;             // N
    float* al2d_ = al2s_ + NNODES;                      // N
    int* rowoff  = (int*)(al2d_ + NNODES);              // N+1
    int* cursor  = rowoff + NNODES + 1;                 // N  (also used as counts)
    int* srcs    = cursor + NNODES;                     // E+N
    int* bsums   = srcs + ETOT;                         // ~391

    const int NB_N   = (NNODES + 255) / 256;   // 391
    const int NB_E   = (NEDGES + 255) / 256;   // 12500
    const int NB_ET  = (ETOT + 255) / 256;     // 12891
    const int NB_N4  = (NNODES + 3) / 4;       // 25000

    // CSR build (counts in `cursor`)
    zero_ints<<<NB_N, 256, 0, stream>>>(cursor, NNODES);
    hist_kernel<<<NB_E, 256, 0, stream>>>(ei, cursor);
    scan1<<<NB_N, 256, 0, stream>>>(cursor, rowoff, bsums);
    scan2<<<1, 512, 0, stream>>>(bsums, NB_N);
    scan3<<<NB_N, 256, 0, stream>>>(rowoff, bsums, cursor);
    scatter_kernel<<<NB_ET, 256, 0, stream>>>(ei, cursor, srcs);

    // layer 1 linear + logits
    gemm1<<<NB_N4, 256, 0, stream>>>(x, W1, a1s, a1d, h1, al1s_, al1d_);

    // layer 1 aggregation + finalize + layer-2 linear/logits
    agg1<<<NB_N4, 256, 0, stream>>>(h1, al1s_, al1d_, b1, W2, a2s, a2d,
                                    rowoff, srcs, h2, al2s_, al2d_);

    // layer 2 aggregation -> output
    agg2<<<NB_N, 256, 0, stream>>>(h2, al2s_, al2d_, b2, rowoff, srcs, out);
}

// Round 2
// 698.620 us; speedup vs baseline: 1.2465x; 1.2465x over previous
//
#include <hip/hip_runtime.h>
#include <math.h>

#define NNODES 100000
#define NEDGES 3200000
#define ETOT   (NEDGES + NNODES)
#define IN_DIM 128
#define NH1    8
#define NC1    8
#define HC     64
#define OUTC   2
#define NEGSL  0.2f

// ---------------- CSR build ----------------

__global__ void zero_ints(int* p, int n) {
    int i = blockIdx.x * blockDim.x + threadIdx.x;
    if (i < n) p[i] = 0;
}

__global__ void hist_kernel(const int* ei, int* cnt) {
    int i = blockIdx.x * blockDim.x + threadIdx.x;
    if (i < NEDGES) atomicAdd(&cnt[ei[NEDGES + i]], 1);
}

// exclusive scan of (cnt[i] + 1) -> rowoff (block-local), block totals -> bsums
__global__ __launch_bounds__(256) void scan1(const int* cnt, int* rowoff, int* bsums) {
    int gid = blockIdx.x * 256 + threadIdx.x;
    int v = (gid < NNODES) ? (cnt[gid] + 1) : 0;   // +1 self-loop per node
    int lane = threadIdx.x & 63, w = threadIdx.x >> 6;
    int x = v;
    for (int off = 1; off < 64; off <<= 1) {
        int y = __shfl_up(x, off, 64);
        if (lane >= off) x += y;
    }
    __shared__ int wtot[4];
    if (lane == 63) wtot[w] = x;
    __syncthreads();
    int add = 0;
    for (int i = 0; i < w; i++) add += wtot[i];
    int incl = x + add;
    if (gid < NNODES) rowoff[gid] = incl - v;      // exclusive within block
    if (threadIdx.x == 255) bsums[blockIdx.x] = incl;
}

__global__ __launch_bounds__(512) void scan2(int* bsums, int nb) {
    int tid = threadIdx.x;
    int v = (tid < nb) ? bsums[tid] : 0;
    int lane = tid & 63, w = tid >> 6;
    int x = v;
    for (int off = 1; off < 64; off <<= 1) {
        int y = __shfl_up(x, off, 64);
        if (lane >= off) x += y;
    }
    __shared__ int wt[8];
    if (lane == 63) wt[w] = x;
    __syncthreads();
    int add = 0;
    for (int i = 0; i < w; i++) add += wt[i];
    if (tid < nb) bsums[tid] = x + add - v;        // exclusive
}

__global__ void scan3(int* rowoff, const int* bsums, int* cursor) {
    int gid = blockIdx.x * blockDim.x + threadIdx.x;
    if (gid < NNODES) {
        int r = rowoff[gid] + bsums[gid >> 8];
        rowoff[gid] = r;
        cursor[gid] = r;
    }
    if (gid == 0) rowoff[NNODES] = ETOT;
}

__global__ void scatter_kernel(const int* ei, int* cursor, int* srcs) {
    int i = blockIdx.x * blockDim.x + threadIdx.x;
    if (i >= ETOT) return;
    int s, d;
    if (i < NEDGES) { s = ei[i]; d = ei[NEDGES + i]; }
    else            { s = d = i - NEDGES; }
    int pos = atomicAdd(&cursor[d], 1);
    srcs[pos] = s;
}

// ---------------- layer 1 linear + attention logits ----------------
// 16 nodes per block (4 per wave); W1 staged once; x via scalar loads
// (node index made wave-uniform with readfirstlane -> s_load path).

__global__ __launch_bounds__(256) void gemm1(const float* __restrict__ x,
                                             const float* __restrict__ W1,
                                             const float* __restrict__ a1s,
                                             const float* __restrict__ a1d,
                                             float* __restrict__ h1,
                                             float* __restrict__ al1s,
                                             float* __restrict__ al1d) {
    __shared__ float sW[IN_DIM * HC];   // 32 KB
    int tid = threadIdx.x;
    const float4* W4 = (const float4*)W1;
    float4* sW4 = (float4*)sW;
#pragma unroll
    for (int i = 0; i < 8; i++)          // 2048 float4 / 256 threads
        sW4[tid + i * 256] = W4[tid + i * 256];
    __syncthreads();

    int w = __builtin_amdgcn_readfirstlane(tid >> 6);
    int lane = tid & 63;
    int node0 = blockIdx.x * 16 + w * 4;       // 6250 blocks * 16 = 100000 exact
    const float* xr = x + (size_t)node0 * IN_DIM;

    float acc0 = 0.f, acc1 = 0.f, acc2 = 0.f, acc3 = 0.f;
#pragma unroll 8
    for (int k = 0; k < IN_DIM; k++) {
        float wv = sW[k * HC + lane];
        acc0 = fmaf(xr[k], wv, acc0);
        acc1 = fmaf(xr[IN_DIM + k], wv, acc1);
        acc2 = fmaf(xr[2 * IN_DIM + k], wv, acc2);
        acc3 = fmaf(xr[3 * IN_DIM + k], wv, acc3);
    }

    float accs[4] = {acc0, acc1, acc2, acc3};
    int head = lane >> 3, c = lane & 7;
    float as = a1s[head * NC1 + c], adv = a1d[head * NC1 + c];
#pragma unroll
    for (int n = 0; n < 4; n++) {
        int node = node0 + n;
        h1[(size_t)node * HC + lane] = accs[n];
        float ps = accs[n] * as;
        float pd = accs[n] * adv;
        for (int off = 1; off < 8; off <<= 1) {
            ps += __shfl_xor(ps, off, 64);
            pd += __shfl_xor(pd, off, 64);
        }
        if (c == 0) {
            al1s[node * NH1 + head] = ps;
            al1d[node * NH1 + head] = pd;
        }
    }
}

// ---------------- layer 1 aggregation ----------------
// wave per node. Phase 1: per-head max of al1s over sources (8 edges x 8
// heads per iteration). LeakyReLU monotonic => max_e = LR(max_als + ald).
// Phase 2: chain-free accumulation p=exp(e-maxe), unrolled x2.
// Epilogue: /den, +b1, ELU, layer-2 linear + logits (fused).

__global__ __launch_bounds__(256) void agg1(const float* __restrict__ h1,
                                            const float* __restrict__ al1s,
                                            const float* __restrict__ al1d,
                                            const float* __restrict__ b1,
                                            const float* __restrict__ W2,
                                            const float* __restrict__ a2s,
                                            const float* __restrict__ a2d,
                                            const int* __restrict__ rowoff,
                                            const int* __restrict__ srcs,
                                            float* __restrict__ h2,
                                            float* __restrict__ al2s,
                                            float* __restrict__ al2d) {
    int w = threadIdx.x >> 6, lane = threadIdx.x & 63;
    int node = blockIdx.x * 4 + w;
    if (node >= NNODES) return;
    int head = lane >> 3;
    float ald = al1d[node * NH1 + head];
    int beg = rowoff[node], end = rowoff[node + 1];

    // phase 1: max over srcs of al1s[s][h]; lane = eslot*8 + h
    float mx = -1e30f;
    {
        int h8 = lane & 7, es = lane >> 3;
        for (int base = beg; base < end; base += 8) {
            int idx = base + es;
            int s = srcs[(idx < end) ? idx : beg];
            mx = fmaxf(mx, al1s[s * NH1 + h8]);
        }
        mx = fmaxf(mx, __shfl_xor(mx, 8, 64));
        mx = fmaxf(mx, __shfl_xor(mx, 16, 64));
        mx = fmaxf(mx, __shfl_xor(mx, 32, 64));
    }
    float me = __shfl(mx, head, 64);         // lane 'head' holds max for that head
    float xm = me + ald;
    float maxe = fmaxf(xm, NEGSL * xm);      // LeakyReLU of max == max of LeakyReLU

    // phase 2: accumulate (no serial rescale chain)
    float den = 0.f, acc = 0.f, denB = 0.f, accB = 0.f;
    int i = beg;
    for (; i + 2 <= end; i += 2) {
        int s0 = srcs[i], s1 = srcs[i + 1];
        float als0 = al1s[s0 * NH1 + head];
        float als1 = al1s[s1 * NH1 + head];
        float hv0 = h1[(size_t)s0 * HC + lane];
        float hv1 = h1[(size_t)s1 * HC + lane];
        float x0 = als0 + ald, x1 = als1 + ald;
        float p0 = __expf(fmaxf(x0, NEGSL * x0) - maxe);
        float p1 = __expf(fmaxf(x1, NEGSL * x1) - maxe);
        den  += p0;  acc  = fmaf(p0, hv0, acc);
        denB += p1;  accB = fmaf(p1, hv1, accB);
    }
    if (i < end) {
        int s0 = srcs[i];
        float als0 = al1s[s0 * NH1 + head];
        float hv0 = h1[(size_t)s0 * HC + lane];
        float x0 = als0 + ald;
        float p0 = __expf(fmaxf(x0, NEGSL * x0) - maxe);
        den += p0; acc = fmaf(p0, hv0, acc);
    }
    den += denB; acc += accB;

    float o = acc / den + b1[lane];
    o = (o > 0.f) ? o : expm1f(o);          // ELU
    // layer-2 linear: h2[node][oc] = sum_lane o * W2[lane][oc]
    float p0 = o * W2[lane * OUTC + 0];
    float p1 = o * W2[lane * OUTC + 1];
    for (int off = 1; off < 64; off <<= 1) {
        p0 += __shfl_xor(p0, off, 64);
        p1 += __shfl_xor(p1, off, 64);
    }
    if (lane == 0) {
        h2[node * 2 + 0] = p0;
        h2[node * 2 + 1] = p1;
        al2s[node] = p0 * a2s[0] + p1 * a2s[1];
        al2d[node] = p0 * a2d[0] + p1 * a2d[1];
    }
}

// ---------------- layer 2 aggregation (wave per node, lane per edge) ----------------

__global__ __launch_bounds__(256) void agg2(const float* __restrict__ h2,
                                            const float* __restrict__ al2s,
                                            const float* __restrict__ al2d,
                                            const float* __restrict__ b2,
                                            const int* __restrict__ rowoff,
                                            const int* __restrict__ srcs,
                                            float* __restrict__ out) {
    int w = threadIdx.x >> 6, lane = threadIdx.x & 63;
    int n = blockIdx.x * 4 + w;
    if (n >= NNODES) return;
    float ald = al2d[n];
    int beg = rowoff[n], end = rowoff[n + 1];
    float m = -1e30f, den = 0.f, a0 = 0.f, a1 = 0.f;
    for (int base = beg; base < end; base += 64) {
        int idx = base + lane;
        bool valid = idx < end;
        int s = valid ? srcs[idx] : 0;
        float e = -1e30f, q0 = 0.f, q1 = 0.f;
        if (valid) {
            float xx = al2s[s] + ald;
            e = fmaxf(xx, NEGSL * xx);
            q0 = h2[s * 2 + 0];
            q1 = h2[s * 2 + 1];
        }
        float cm = e;
        for (int off = 1; off < 64; off <<= 1) cm = fmaxf(cm, __shfl_xor(cm, off, 64));
        float nm = fmaxf(m, cm);
        float sc = __expf(m - nm);
        float p = valid ? __expf(e - nm) : 0.f;
        float pd = p, pa0 = p * q0, pa1 = p * q1;
        for (int off = 1; off < 64; off <<= 1) {
            pd  += __shfl_xor(pd, off, 64);
            pa0 += __shfl_xor(pa0, off, 64);
            pa1 += __shfl_xor(pa1, off, 64);
        }
        den = den * sc + pd;
        a0  = a0 * sc + pa0;
        a1  = a1 * sc + pa1;
        m = nm;
    }
    if (lane == 0) {
        out[n * 2 + 0] = a0 / den + b2[0];
        out[n * 2 + 1] = a1 / den + b2[1];
    }
}

// ---------------- launch ----------------

extern "C" void kernel_launch(void* const* d_in, const int* in_sizes, int n_in,
                              void* d_out, int out_size, void* d_ws, size_t ws_size,
                              hipStream_t stream) {
    const float* x   = (const float*)d_in[0];
    const int*   ei  = (const int*)  d_in[1];
    // d_in[2] = edge_attr (unused by reference)
    const float* W1  = (const float*)d_in[3];
    const float* a1s = (const float*)d_in[4];
    const float* a1d = (const float*)d_in[5];
    const float* b1  = (const float*)d_in[6];
    const float* W2  = (const float*)d_in[7];
    const float* a2s = (const float*)d_in[8];
    const float* a2d = (const float*)d_in[9];
    const float* b2  = (const float*)d_in[10];
    float* out = (float*)d_out;

    // workspace layout
    float* fws   = (float*)d_ws;
    float* h1    = fws;                                 // N*64
    float* al1s_ = h1 + (size_t)NNODES * HC;            // N*8
    float* al1d_ = al1s_ + (size_t)NNODES * NH1;        // N*8
    float* h2    = al1d_ + (size_t)NNODES * NH1;        // N*2
    float* al2s_ = h2 + (size_t)NNODES * 2;             // N
    float* al2d_ = al2s_ + NNODES;                      // N
    int* rowoff  = (int*)(al2d_ + NNODES);              // N+1
    int* cursor  = rowoff + NNODES + 1;                 // N  (also used as counts)
    int* srcs    = cursor + NNODES;                     // E+N
    int* bsums   = srcs + ETOT;                         // ~391

    const int NB_N   = (NNODES + 255) / 256;   // 391
    const int NB_E   = (NEDGES + 255) / 256;   // 12500
    const int NB_ET  = (ETOT + 255) / 256;     // 12891
    const int NB_N4  = (NNODES + 3) / 4;       // 25000
    const int NB_G   = NNODES / 16;            // 6250 (exact)

    // CSR build (counts in `cursor`)
    zero_ints<<<NB_N, 256, 0, stream>>>(cursor, NNODES);
    hist_kernel<<<NB_E, 256, 0, stream>>>(ei, cursor);
    scan1<<<NB_N, 256, 0, stream>>>(cursor, rowoff, bsums);
    scan2<<<1, 512, 0, stream>>>(bsums, NB_N);
    scan3<<<NB_N, 256, 0, stream>>>(rowoff, bsums, cursor);
    scatter_kernel<<<NB_ET, 256, 0, stream>>>(ei, cursor, srcs);

    // layer 1 linear + logits
    gemm1<<<NB_G, 256, 0, stream>>>(x, W1, a1s, a1d, h1, al1s_, al1d_);

    // layer 1 aggregation + finalize + layer-2 linear/logits
    agg1<<<NB_N4, 256, 0, stream>>>(h1, al1s_, al1d_, b1, W2, a2s, a2d,
                                    rowoff, srcs, h2, al2s_, al2d_);

    // layer 2 aggregation -> output
    agg2<<<NB_N4, 256, 0, stream>>>(h2, al2s_, al2d_, b2, rowoff, srcs, out);
}

// Round 3
// 486.264 us; speedup vs baseline: 1.7909x; 1.4367x over previous
//
#include <hip/hip_runtime.h>
#include <math.h>

#define NNODES 100000
#define NEDGES 3200000
#define ETOT   (NEDGES + NNODES)
#define IN_DIM 128
#define NH1    8
#define NC1    8
#define HC     64
#define OUTC   2
#define NEGSL  0.2f

// ---------------- CSR build ----------------

__global__ void zero_ints(int* p, int n) {
    int i = blockIdx.x * blockDim.x + threadIdx.x;
    if (i < n) p[i] = 0;
}

// histogram + per-edge rank (the atomic's return value IS the rank; writing it
// coalesced lets the scatter pass run atomic-free)
__global__ void hist_rank(const int* ei, int* cnt, int* rank) {
    int i = blockIdx.x * blockDim.x + threadIdx.x;
    if (i < NEDGES) {
        int d = ei[NEDGES + i];
        rank[i] = atomicAdd(&cnt[d], 1);
    }
}

// exclusive scan of (cnt[i] + 1) -> rowoff (block-local), block totals -> bsums
__global__ __launch_bounds__(256) void scan1(const int* cnt, int* rowoff, int* bsums) {
    int gid = blockIdx.x * 256 + threadIdx.x;
    int v = (gid < NNODES) ? (cnt[gid] + 1) : 0;   // +1 self-loop per node
    int lane = threadIdx.x & 63, w = threadIdx.x >> 6;
    int x = v;
    for (int off = 1; off < 64; off <<= 1) {
        int y = __shfl_up(x, off, 64);
        if (lane >= off) x += y;
    }
    __shared__ int wtot[4];
    if (lane == 63) wtot[w] = x;
    __syncthreads();
    int add = 0;
    for (int i = 0; i < w; i++) add += wtot[i];
    int incl = x + add;
    if (gid < NNODES) rowoff[gid] = incl - v;      // exclusive within block
    if (threadIdx.x == 255) bsums[blockIdx.x] = incl;
}

__global__ __launch_bounds__(512) void scan2(int* bsums, int nb) {
    int tid = threadIdx.x;
    int v = (tid < nb) ? bsums[tid] : 0;
    int lane = tid & 63, w = tid >> 6;
    int x = v;
    for (int off = 1; off < 64; off <<= 1) {
        int y = __shfl_up(x, off, 64);
        if (lane >= off) x += y;
    }
    __shared__ int wt[8];
    if (lane == 63) wt[w] = x;
    __syncthreads();
    int add = 0;
    for (int i = 0; i < w; i++) add += wt[i];
    if (tid < nb) bsums[tid] = x + add - v;        // exclusive
}

__global__ void scan3(int* rowoff, const int* bsums) {
    int gid = blockIdx.x * blockDim.x + threadIdx.x;
    if (gid < NNODES) rowoff[gid] = rowoff[gid] + bsums[gid >> 8];
    if (gid == 0) rowoff[NNODES] = ETOT;
}

// atomic-free scatter: position fully determined by rowoff + precomputed rank
__global__ void scatter2(const int* __restrict__ ei, const int* __restrict__ rank,
                         const int* __restrict__ rowoff, int* __restrict__ srcs) {
    int i = blockIdx.x * blockDim.x + threadIdx.x;
    if (i >= ETOT) return;
    if (i < NEDGES) {
        int d = ei[NEDGES + i];
        srcs[rowoff[d] + rank[i]] = ei[i];
    } else {
        int n = i - NEDGES;
        srcs[rowoff[n + 1] - 1] = n;   // self-loop in the last slot of its row
    }
}

// ---------------- layer 1 linear + attention logits ----------------
// 16 nodes per block (4 per wave); W1 staged once; x via scalar loads
// (node index made wave-uniform with readfirstlane -> s_load path).

__global__ __launch_bounds__(256) void gemm1(const float* __restrict__ x,
                                             const float* __restrict__ W1,
                                             const float* __restrict__ a1s,
                                             const float* __restrict__ a1d,
                                             float* __restrict__ h1,
                                             float* __restrict__ al1s,
                                             float* __restrict__ al1d) {
    __shared__ float sW[IN_DIM * HC];   // 32 KB
    int tid = threadIdx.x;
    const float4* W4 = (const float4*)W1;
    float4* sW4 = (float4*)sW;
#pragma unroll
    for (int i = 0; i < 8; i++)          // 2048 float4 / 256 threads
        sW4[tid + i * 256] = W4[tid + i * 256];
    __syncthreads();

    int w = __builtin_amdgcn_readfirstlane(tid >> 6);
    int lane = tid & 63;
    int node0 = blockIdx.x * 16 + w * 4;       // 6250 blocks * 16 = 100000 exact
    const float* xr = x + (size_t)node0 * IN_DIM;

    float acc0 = 0.f, acc1 = 0.f, acc2 = 0.f, acc3 = 0.f;
#pragma unroll 8
    for (int k = 0; k < IN_DIM; k++) {
        float wv = sW[k * HC + lane];
        acc0 = fmaf(xr[k], wv, acc0);
        acc1 = fmaf(xr[IN_DIM + k], wv, acc1);
        acc2 = fmaf(xr[2 * IN_DIM + k], wv, acc2);
        acc3 = fmaf(xr[3 * IN_DIM + k], wv, acc3);
    }

    float accs[4] = {acc0, acc1, acc2, acc3};
    int head = lane >> 3, c = lane & 7;
    float as = a1s[head * NC1 + c], adv = a1d[head * NC1 + c];
#pragma unroll
    for (int n = 0; n < 4; n++) {
        int node = node0 + n;
        h1[(size_t)node * HC + lane] = accs[n];
        float ps = accs[n] * as;
        float pd = accs[n] * adv;
        for (int off = 1; off < 8; off <<= 1) {
            ps += __shfl_xor(ps, off, 64);
            pd += __shfl_xor(pd, off, 64);
        }
        if (c == 0) {
            al1s[node * NH1 + head] = ps;
            al1d[node * NH1 + head] = pd;
        }
    }
}

// ---------------- layer 1 aggregation ----------------
// wave per node. Phase 1: per-head max of al1s over sources (8 edges x 8
// heads per iteration). LeakyReLU monotonic => max_e = LR(max_als + ald).
// Phase 2: chain-free accumulation p=exp(e-maxe), unrolled x2.
// Epilogue: /den, +b1, ELU, layer-2 linear + logits (fused).

__global__ __launch_bounds__(256) void agg1(const float* __restrict__ h1,
                                            const float* __restrict__ al1s,
                                            const float* __restrict__ al1d,
                                            const float* __restrict__ b1,
                                            const float* __restrict__ W2,
                                            const float* __restrict__ a2s,
                                            const float* __restrict__ a2d,
                                            const int* __restrict__ rowoff,
                                            const int* __restrict__ srcs,
                                            float* __restrict__ h2,
                                            float* __restrict__ al2s,
                                            float* __restrict__ al2d) {
    int w = threadIdx.x >> 6, lane = threadIdx.x & 63;
    int node = blockIdx.x * 4 + w;
    if (node >= NNODES) return;
    int head = lane >> 3;
    float ald = al1d[node * NH1 + head];
    int beg = rowoff[node], end = rowoff[node + 1];

    // phase 1: max over srcs of al1s[s][h]; lane = eslot*8 + h
    float mx = -1e30f;
    {
        int h8 = lane & 7, es = lane >> 3;
        for (int base = beg; base < end; base += 8) {
            int idx = base + es;
            int s = srcs[(idx < end) ? idx : beg];
            mx = fmaxf(mx, al1s[s * NH1 + h8]);
        }
        mx = fmaxf(mx, __shfl_xor(mx, 8, 64));
        mx = fmaxf(mx, __shfl_xor(mx, 16, 64));
        mx = fmaxf(mx, __shfl_xor(mx, 32, 64));
    }
    float me = __shfl(mx, head, 64);         // lane 'head' holds max for that head
    float xm = me + ald;
    float maxe = fmaxf(xm, NEGSL * xm);      // LeakyReLU of max == max of LeakyReLU

    // phase 2: accumulate (no serial rescale chain)
    float den = 0.f, acc = 0.f, denB = 0.f, accB = 0.f;
    int i = beg;
    for (; i + 2 <= end; i += 2) {
        int s0 = srcs[i], s1 = srcs[i + 1];
        float als0 = al1s[s0 * NH1 + head];
        float als1 = al1s[s1 * NH1 + head];
        float hv0 = h1[(size_t)s0 * HC + lane];
        float hv1 = h1[(size_t)s1 * HC + lane];
        float x0 = als0 + ald, x1 = als1 + ald;
        float p0 = __expf(fmaxf(x0, NEGSL * x0) - maxe);
        float p1 = __expf(fmaxf(x1, NEGSL * x1) - maxe);
        den  += p0;  acc  = fmaf(p0, hv0, acc);
        denB += p1;  accB = fmaf(p1, hv1, accB);
    }
    if (i < end) {
        int s0 = srcs[i];
        float als0 = al1s[s0 * NH1 + head];
        float hv0 = h1[(size_t)s0 * HC + lane];
        float x0 = als0 + ald;
        float p0 = __expf(fmaxf(x0, NEGSL * x0) - maxe);
        den += p0; acc = fmaf(p0, hv0, acc);
    }
    den += denB; acc += accB;

    float o = acc / den + b1[lane];
    o = (o > 0.f) ? o : expm1f(o);          // ELU
    // layer-2 linear: h2[node][oc] = sum_lane o * W2[lane][oc]
    float p0 = o * W2[lane * OUTC + 0];
    float p1 = o * W2[lane * OUTC + 1];
    for (int off = 1; off < 64; off <<= 1) {
        p0 += __shfl_xor(p0, off, 64);
        p1 += __shfl_xor(p1, off, 64);
    }
    if (lane == 0) {
        h2[node * 2 + 0] = p0;
        h2[node * 2 + 1] = p1;
        al2s[node] = p0 * a2s[0] + p1 * a2s[1];
        al2d[node] = p0 * a2d[0] + p1 * a2d[1];
    }
}

// ---------------- layer 2 aggregation (wave per node, lane per edge) ----------------

__global__ __launch_bounds__(256) void agg2(const float* __restrict__ h2,
                                            const float* __restrict__ al2s,
                                            const float* __restrict__ al2d,
                                            const float* __restrict__ b2,
                                            const int* __restrict__ rowoff,
                                            const int* __restrict__ srcs,
                                            float* __restrict__ out) {
    int w = threadIdx.x >> 6, lane = threadIdx.x & 63;
    int n = blockIdx.x * 4 + w;
    if (n >= NNODES) return;
    float ald = al2d[n];
    int beg = rowoff[n], end = rowoff[n + 1];
    float m = -1e30f, den = 0.f, a0 = 0.f, a1 = 0.f;
    for (int base = beg; base < end; base += 64) {
        int idx = base + lane;
        bool valid = idx < end;
        int s = valid ? srcs[idx] : 0;
        float e = -1e30f, q0 = 0.f, q1 = 0.f;
        if (valid) {
            float xx = al2s[s] + ald;
            e = fmaxf(xx, NEGSL * xx);
            q0 = h2[s * 2 + 0];
            q1 = h2[s * 2 + 1];
        }
        float cm = e;
        for (int off = 1; off < 64; off <<= 1) cm = fmaxf(cm, __shfl_xor(cm, off, 64));
        float nm = fmaxf(m, cm);
        float sc = __expf(m - nm);
        float p = valid ? __expf(e - nm) : 0.f;
        float pd = p, pa0 = p * q0, pa1 = p * q1;
        for (int off = 1; off < 64; off <<= 1) {
            pd  += __shfl_xor(pd, off, 64);
            pa0 += __shfl_xor(pa0, off, 64);
            pa1 += __shfl_xor(pa1, off, 64);
        }
        den = den * sc + pd;
        a0  = a0 * sc + pa0;
        a1  = a1 * sc + pa1;
        m = nm;
    }
    if (lane == 0) {
        out[n * 2 + 0] = a0 / den + b2[0];
        out[n * 2 + 1] = a1 / den + b2[1];
    }
}

// ---------------- launch ----------------

extern "C" void kernel_launch(void* const* d_in, const int* in_sizes, int n_in,
                              void* d_out, int out_size, void* d_ws, size_t ws_size,
                              hipStream_t stream) {
    const float* x   = (const float*)d_in[0];
    const int*   ei  = (const int*)  d_in[1];
    // d_in[2] = edge_attr (unused by reference)
    const float* W1  = (const float*)d_in[3];
    const float* a1s = (const float*)d_in[4];
    const float* a1d = (const float*)d_in[5];
    const float* b1  = (const float*)d_in[6];
    const float* W2  = (const float*)d_in[7];
    const float* a2s = (const float*)d_in[8];
    const float* a2d = (const float*)d_in[9];
    const float* b2  = (const float*)d_in[10];
    float* out = (float*)d_out;

    // workspace layout. NOTE: rank aliases h1 — rank is only live during the
    // CSR build; h1 is first written by gemm1, which launches after scatter2.
    float* fws   = (float*)d_ws;
    float* h1    = fws;                                 // N*64 floats (25.6MB)
    int*   rank  = (int*)fws;                           // E ints (12.8MB) — aliases h1
    float* al1s_ = h1 + (size_t)NNODES * HC;            // N*8
    float* al1d_ = al1s_ + (size_t)NNODES * NH1;        // N*8
    float* h2    = al1d_ + (size_t)NNODES * NH1;        // N*2
    float* al2s_ = h2 + (size_t)NNODES * 2;             // N
    float* al2d_ = al2s_ + NNODES;                      // N
    int* rowoff  = (int*)(al2d_ + NNODES);              // N+1
    int* cnt     = rowoff + NNODES + 1;                 // N
    int* srcs    = cnt + NNODES;                        // E+N
    int* bsums   = srcs + ETOT;                         // ~391

    const int NB_N   = (NNODES + 255) / 256;   // 391
    const int NB_E   = (NEDGES + 255) / 256;   // 12500
    const int NB_ET  = (ETOT + 255) / 256;     // 12891
    const int NB_N4  = (NNODES + 3) / 4;       // 25000
    const int NB_G   = NNODES / 16;            // 6250 (exact)

    // CSR build
    zero_ints<<<NB_N, 256, 0, stream>>>(cnt, NNODES);
    hist_rank<<<NB_E, 256, 0, stream>>>(ei, cnt, rank);
    scan1<<<NB_N, 256, 0, stream>>>(cnt, rowoff, bsums);
    scan2<<<1, 512, 0, stream>>>(bsums, NB_N);
    scan3<<<NB_N, 256, 0, stream>>>(rowoff, bsums);
    scatter2<<<NB_ET, 256, 0, stream>>>(ei, rank, rowoff, srcs);

    // layer 1 linear + logits
    gemm1<<<NB_G, 256, 0, stream>>>(x, W1, a1s, a1d, h1, al1s_, al1d_);

    // layer 1 aggregation + finalize + layer-2 linear/logits
    agg1<<<NB_N4, 256, 0, stream>>>(h1, al1s_, al1d_, b1, W2, a2s, a2d,
                                    rowoff, srcs, h2, al2s_, al2d_);

    // layer 2 aggregation -> output
    agg2<<<NB_N4, 256, 0, stream>>>(h2, al2s_, al2d_, b2, rowoff, srcs, out);
}